// Round 4
// baseline (894.710 us; speedup 1.0000x reference)
//
#include <hip/hip_runtime.h>
#include <hip/hip_bf16.h>

#define F 64
#define GRAPHS 512
#define CLASSES 10
#define SCAN_T 1024

// ---------------- deg (real edges only) + graph bounds fused ----------------
__global__ void deg_gb_kernel(const int* __restrict__ ei, int E, int* __restrict__ deg,
                              const int* __restrict__ batch, int N, int* __restrict__ gstart,
                              int DB) {
    int b = blockIdx.x;
    if (b < DB) {
        int i = b * 256 + threadIdx.x;
        if (i < E) atomicAdd(&deg[ei[E + i]], 1);
    } else {
        int g = (b - DB) * 256 + threadIdx.x;
        if (g > GRAPHS) return;
        int lo = 0, hi = N;
        while (lo < hi) {
            int mid = (lo + hi) >> 1;
            if (batch[mid] < g) lo = mid + 1; else hi = mid;
        }
        gstart[g] = lo;
    }
}

// ---------------- scan (degree = deg[i] + 1 for the self loop) ----------------
__global__ void scan_partial(const int* __restrict__ deg, int N, int* __restrict__ partial) {
    int t = blockIdx.x * blockDim.x + threadIdx.x;
    int chunk = (N + SCAN_T - 1) / SCAN_T;
    int b = t * chunk;
    int e = min(N, b + chunk);
    int s = 0;
    for (int i = b; i < e; ++i) s += deg[i] + 1;
    partial[t] = s;
}

__global__ void scan_block(int* __restrict__ partial) {   // 1 block, 1024 threads
    __shared__ int wsum[16];
    int t = threadIdx.x;
    int lane = t & 63, w = t >> 6;
    int orig = partial[t];
    int v = orig;
    #pragma unroll
    for (int o = 1; o < 64; o <<= 1) {
        int u = __shfl_up(v, o);
        if (lane >= o) v += u;
    }
    if (lane == 63) wsum[w] = v;
    __syncthreads();
    if (t == 0) {
        int run = 0;
        for (int i = 0; i < 16; ++i) { int x = wsum[i]; wsum[i] = run; run += x; }
    }
    __syncthreads();
    v += wsum[w];
    partial[t] = v - orig;   // exclusive prefix
}

// writes rowptr, fill (=segment start), and the self-loop entry at segment end
__global__ void scan_final(const int* __restrict__ deg, const int* __restrict__ partial,
                           int N, int* __restrict__ rowptr, int* __restrict__ fill,
                           int* __restrict__ csr_src) {
    int t = blockIdx.x * blockDim.x + threadIdx.x;
    int chunk = (N + SCAN_T - 1) / SCAN_T;
    int b = t * chunk;
    int e = min(N, b + chunk);
    int run = partial[t];
    for (int i = b; i < e; ++i) {
        rowptr[i] = run;
        fill[i] = run;
        int d = deg[i];
        csr_src[run + d] = i;   // self loop at end of segment
        run += d + 1;
    }
    if (t == SCAN_T - 1) rowptr[N] = run;
}

// ---------------- GEMM body (shared by fused + standalone kernels) ----------------
// h = x@W with fused e_src/e_dst epilogue. W transposed into padded LDS so each
// lane reads its own column via ds_read_b128 (row stride K+4 floats: 16B aligned,
// bank pattern 8/bank = LDS-BW-optimal).
template<int K>
__device__ __forceinline__ void gemm_body(float* smem,
                                          const float* __restrict__ x, const float* __restrict__ W,
                                          const float* __restrict__ asrc, const float* __restrict__ adst,
                                          float* __restrict__ h, float* __restrict__ es,
                                          float* __restrict__ ed, int N, int bid) {
    constexpr int ROWS = 16;
    constexpr int KP = K + 4;
    constexpr int K4 = K / 4;
    float* Ws = smem;              // [64][KP] transposed
    float* xs = smem + 64 * KP;    // [ROWS][K]
    int base = bid * ROWS;

    const float4* W4 = (const float4*)W;
    for (int i = threadIdx.x; i < K * F / 4; i += 256) {
        float4 v = W4[i];
        int k = (4 * i) >> 6;
        int c = (4 * i) & 63;
        Ws[(c + 0) * KP + k] = v.x;
        Ws[(c + 1) * KP + k] = v.y;
        Ws[(c + 2) * KP + k] = v.z;
        Ws[(c + 3) * KP + k] = v.w;
    }
    int nrows = min(ROWS, N - base);
    float4* xs4 = (float4*)xs;
    const float4* x4 = (const float4*)x;
    for (int i = threadIdx.x; i < nrows * K4; i += 256) {
        int r = i / K4, k4 = i - r * K4;
        xs4[r * K4 + k4] = x4[(size_t)(base + r) * K4 + k4];
    }
    __syncthreads();

    int wave = threadIdx.x >> 6, lane = threadIdx.x & 63;
    float as_l = asrc[lane];
    float ad_l = adst[lane];
    const float4* wr = (const float4*)&Ws[lane * KP];
    for (int r = wave; r < nrows; r += 4) {
        const float4* xr = (const float4*)&xs[r * K];
        float a0 = 0.f, a1 = 0.f, a2 = 0.f, a3 = 0.f;
        #pragma unroll
        for (int k4 = 0; k4 < K4; ++k4) {
            float4 xv = xr[k4];
            float4 wv = wr[k4];
            a0 = fmaf(xv.x, wv.x, a0);
            a1 = fmaf(xv.y, wv.y, a1);
            a2 = fmaf(xv.z, wv.z, a2);
            a3 = fmaf(xv.w, wv.w, a3);
        }
        float acc = (a0 + a1) + (a2 + a3);
        h[(size_t)(base + r) * F + lane] = acc;
        float vs = acc * as_l;
        float vd = acc * ad_l;
        #pragma unroll
        for (int o = 32; o > 0; o >>= 1) {
            vs += __shfl_down(vs, o);
            vd += __shfl_down(vd, o);
        }
        if (lane == 0) { es[base + r] = vs; ed[base + r] = vd; }
    }
}

// ---------------- fused: edge scatter (real edges) + layer-1 GEMM ----------------
// Scatter is device-throughput-bound (fabric atomics + random-line writes), so the
// gemm blocks ride along for free; agg1 needs both products anyway.
__global__ void scatter_gemm1(const int* __restrict__ ei, int E,
                              int* __restrict__ fill, int* __restrict__ csr_src,
                              const float* __restrict__ x, const float* __restrict__ W,
                              const float* __restrict__ asrc, const float* __restrict__ adst,
                              float* __restrict__ h, float* __restrict__ es, float* __restrict__ ed,
                              int N, int SB, int GB) {
    extern __shared__ float smem[];
    int b = blockIdx.x;
    int half = min(SB, GB);
    int sid = -1, gid = -1;
    if (b < 2 * half) {
        if (b & 1) gid = b >> 1; else sid = b >> 1;
    } else {
        int r = b - 2 * half;
        if (SB > GB) sid = half + r; else gid = half + r;
    }
    if (sid >= 0) {
        int i = sid * 256 + threadIdx.x;
        if (i < E) {
            int s = ei[i], d = ei[E + i];
            int pos = atomicAdd(&fill[d], 1);
            csr_src[pos] = s;
        }
    } else {
        gemm_body<128>(smem, x, W, asrc, adst, h, es, ed, N, gid);
    }
}

__global__ void gemm64_kernel(const float* __restrict__ x, const float* __restrict__ W,
                              const float* __restrict__ asrc, const float* __restrict__ adst,
                              float* __restrict__ h, float* __restrict__ es, float* __restrict__ ed,
                              int N) {
    extern __shared__ float smem[];
    gemm_body<64>(smem, x, W, asrc, adst, h, es, ed, N, blockIdx.x);
}

// ---------------- per-node segment softmax + aggregation ----------------
__global__ void gat_aggregate(const float* __restrict__ h, const float* __restrict__ es,
                              const float* __restrict__ ed, const int* __restrict__ rowptr,
                              const int* __restrict__ csr_src, const float* __restrict__ bias,
                              float* __restrict__ xout, int N) {
    __shared__ float2 sw[4][64];
    int wave = threadIdx.x >> 6, lane = threadIdx.x & 63;
    int node = blockIdx.x * 4 + wave;
    if (node >= N) return;
    int beg = rowptr[node], end = rowptr[node + 1];
    int cnt = end - beg;
    float edn = ed[node];
    float acc;

    if (cnt <= 64) {
        int s = 0;
        float e = -1e30f;
        if (lane < cnt) {
            s = csr_src[beg + lane];
            float t = es[s] + edn;
            e = t > 0.f ? t : 0.2f * t;
        }
        float m = e;
        #pragma unroll
        for (int o = 32; o > 0; o >>= 1) m = fmaxf(m, __shfl_xor(m, o));
        float w = (lane < cnt) ? __expf(e - m) : 0.f;
        float den = w;
        #pragma unroll
        for (int o = 32; o > 0; o >>= 1) den += __shfl_xor(den, o);
        sw[wave][lane] = make_float2(__int_as_float(s), w);
        float a0 = 0.f, a1 = 0.f, a2 = 0.f, a3 = 0.f;
        int i = 0;
        for (; i + 3 < cnt; i += 4) {
            float2 p0 = sw[wave][i];
            float2 p1 = sw[wave][i + 1];
            float2 p2 = sw[wave][i + 2];
            float2 p3 = sw[wave][i + 3];
            float h0 = h[(size_t)__float_as_int(p0.x) * F + lane];
            float h1 = h[(size_t)__float_as_int(p1.x) * F + lane];
            float h2 = h[(size_t)__float_as_int(p2.x) * F + lane];
            float h3 = h[(size_t)__float_as_int(p3.x) * F + lane];
            a0 = fmaf(p0.y, h0, a0);
            a1 = fmaf(p1.y, h1, a1);
            a2 = fmaf(p2.y, h2, a2);
            a3 = fmaf(p3.y, h3, a3);
        }
        for (; i < cnt; ++i) {
            float2 p = sw[wave][i];
            a0 = fmaf(p.y, h[(size_t)__float_as_int(p.x) * F + lane], a0);
        }
        acc = ((a0 + a1) + (a2 + a3)) / (den + 1e-16f);
    } else {
        float m = -1e30f;
        for (int j = beg + lane; j < end; j += 64) {
            float e = es[csr_src[j]] + edn;
            e = e > 0.f ? e : 0.2f * e;
            m = fmaxf(m, e);
        }
        #pragma unroll
        for (int o = 32; o > 0; o >>= 1) m = fmaxf(m, __shfl_xor(m, o));
        float a = 0.f, den = 0.f;
        for (int j = beg; j < end; ++j) {
            int s = csr_src[j];
            float e = es[s] + edn;
            e = e > 0.f ? e : 0.2f * e;
            float w = __expf(e - m);
            den += w;
            a = fmaf(w, h[(size_t)s * F + lane], a);
        }
        acc = a / (den + 1e-16f);
    }
    float v = acc + bias[lane];
    v = v > 0.f ? v : 0.f;   // relu
    xout[(size_t)node * F + lane] = v;
}

// ---------------- mean pooling: 4 blocks per graph, register accumulate ----------------
__global__ void pool_kernel(const float* __restrict__ x1, const float* __restrict__ x2,
                            const float* __restrict__ x3, const int* __restrict__ gstart,
                            float* __restrict__ pooled) {
    int g = blockIdx.x >> 2;
    int seg = blockIdx.x & 3;
    int f = threadIdx.x;               // 0..191
    int lane = f & 63;
    const float* src = (f < 64) ? x1 : (f < 128) ? x2 : x3;
    int lo = gstart[g], hi = gstart[g + 1];
    int len = hi - lo;
    int chunk = (len + 3) >> 2;
    int b = lo + seg * chunk;
    int e = min(hi, b + chunk);
    float s0 = 0.f, s1 = 0.f, s2 = 0.f, s3 = 0.f;
    int i = b;
    for (; i + 3 < e; i += 4) {
        s0 += src[(size_t)i * F + lane];
        s1 += src[(size_t)(i + 1) * F + lane];
        s2 += src[(size_t)(i + 2) * F + lane];
        s3 += src[(size_t)(i + 3) * F + lane];
    }
    for (; i < e; ++i) s0 += src[(size_t)i * F + lane];
    float s = (s0 + s1) + (s2 + s3);
    atomicAdd(&pooled[g * 192 + f], s);
}

// ---------------- final linear + softmax ----------------
__global__ void head_kernel(const float* __restrict__ pooled, const int* __restrict__ gstart,
                            const float* __restrict__ Wo, const float* __restrict__ bo,
                            float* __restrict__ out) {
    int g = blockIdx.x * blockDim.x + threadIdx.x;
    if (g >= GRAPHS) return;
    int cntg = gstart[g + 1] - gstart[g];
    float inv = 1.0f / fmaxf((float)cntg, 1.0f);
    float acc[CLASSES];
    #pragma unroll
    for (int c = 0; c < CLASSES; ++c) acc[c] = bo[c];
    for (int f = 0; f < 192; ++f) {
        float p = pooled[g * 192 + f] * inv;
        #pragma unroll
        for (int c = 0; c < CLASSES; ++c) acc[c] = fmaf(p, Wo[f * CLASSES + c], acc[c]);
    }
    float mx = acc[0];
    #pragma unroll
    for (int c = 1; c < CLASSES; ++c) mx = fmaxf(mx, acc[c]);
    float s = 0.f;
    #pragma unroll
    for (int c = 0; c < CLASSES; ++c) { acc[c] = __expf(acc[c] - mx); s += acc[c]; }
    float invs = 1.0f / s;
    #pragma unroll
    for (int c = 0; c < CLASSES; ++c) out[g * CLASSES + c] = acc[c] * invs;
}

extern "C" void kernel_launch(void* const* d_in, const int* in_sizes, int n_in,
                              void* d_out, int out_size, void* d_ws, size_t ws_size,
                              hipStream_t stream) {
    const float* x   = (const float*)d_in[0];
    const int* ei    = (const int*)d_in[1];
    const int* batch = (const int*)d_in[2];
    const float* W1  = (const float*)d_in[3];
    const float* a1s = (const float*)d_in[4];
    const float* a1d = (const float*)d_in[5];
    const float* b1  = (const float*)d_in[6];
    const float* W2  = (const float*)d_in[7];
    const float* a2s = (const float*)d_in[8];
    const float* a2d = (const float*)d_in[9];
    const float* b2  = (const float*)d_in[10];
    const float* W3  = (const float*)d_in[11];
    const float* a3s = (const float*)d_in[12];
    const float* a3d = (const float*)d_in[13];
    const float* b3  = (const float*)d_in[14];
    const float* Wo  = (const float*)d_in[15];
    const float* bo  = (const float*)d_in[16];
    float* out = (float*)d_out;

    const int N = in_sizes[2];          // #nodes
    const int E = in_sizes[1] / 2;      // real edges
    const int TOT = E + N;              // with self loops

    char* p = (char*)d_ws;
    auto alloc = [&](size_t bytes) { char* r = p; p += (bytes + 255) & ~(size_t)255; return r; };
    float* x1     = (float*)alloc((size_t)N * F * 4);
    float* x2     = (float*)alloc((size_t)N * F * 4);
    float* x3     = (float*)alloc((size_t)N * F * 4);
    float* h      = (float*)alloc((size_t)N * F * 4);
    float* es     = (float*)alloc((size_t)N * 4);
    float* ed     = (float*)alloc((size_t)N * 4);
    int* deg      = (int*)alloc((size_t)N * 4);
    int* rowptr   = (int*)alloc((size_t)(N + 1) * 4);
    int* fill     = (int*)alloc((size_t)N * 4);
    int* csr_src  = (int*)alloc((size_t)TOT * 4);
    int* partial  = (int*)alloc((size_t)SCAN_T * 4);
    float* pooled = (float*)alloc((size_t)GRAPHS * 192 * 4);
    int* gstart   = (int*)alloc((size_t)(GRAPHS + 1) * 4);

    hipMemsetAsync(deg, 0, (size_t)N * 4, stream);
    hipMemsetAsync(pooled, 0, (size_t)GRAPHS * 192 * 4, stream);

    const int DB = (E + 255) / 256;
    const int SB = (E + 255) / 256;
    const int GB = (N + 15) / 16;
    const size_t SM128 = (size_t)(64 * 132 + 16 * 128) * 4;   // 41984 B
    const size_t SM64  = (size_t)(64 * 68 + 16 * 64) * 4;     // 21504 B
    int node_blocks = (N + 3) / 4;

    // CSR build prefix (deg over real edges; gbounds rides along)
    deg_gb_kernel<<<DB + 3, 256, 0, stream>>>(ei, E, deg, batch, N, gstart, DB);
    scan_partial<<<SCAN_T / 256, 256, 0, stream>>>(deg, N, partial);
    scan_block<<<1, SCAN_T, 0, stream>>>(partial);
    scan_final<<<SCAN_T / 256, 256, 0, stream>>>(deg, partial, N, rowptr, fill, csr_src);

    // fused scatter + layer-1 GEMM
    scatter_gemm1<<<SB + GB, 256, SM128, stream>>>(ei, E, fill, csr_src,
                                                   x, W1, a1s, a1d, h, es, ed, N, SB, GB);
    gat_aggregate<<<node_blocks, 256, 0, stream>>>(h, es, ed, rowptr, csr_src, b1, x1, N);
    // layer 2
    gemm64_kernel<<<GB, 256, SM64, stream>>>(x1, W2, a2s, a2d, h, es, ed, N);
    gat_aggregate<<<node_blocks, 256, 0, stream>>>(h, es, ed, rowptr, csr_src, b2, x2, N);
    // layer 3
    gemm64_kernel<<<GB, 256, SM64, stream>>>(x2, W3, a3s, a3d, h, es, ed, N);
    gat_aggregate<<<node_blocks, 256, 0, stream>>>(h, es, ed, rowptr, csr_src, b3, x3, N);

    // readout
    pool_kernel<<<GRAPHS * 4, 192, 0, stream>>>(x1, x2, x3, gstart, pooled);
    head_kernel<<<(GRAPHS + 255) / 256, 256, 0, stream>>>(pooled, gstart, Wo, bo, out);
}

// Round 5
// 821.778 us; speedup vs baseline: 1.0888x; 1.0888x over previous
//
#include <hip/hip_runtime.h>
#include <hip/hip_bf16.h>

#define F 64
#define GRAPHS 512
#define CLASSES 10
#define SCAN_T 1024

// ---------------- deg (real edges only) + graph bounds fused ----------------
__global__ void deg_gb_kernel(const int* __restrict__ ei, int E, int* __restrict__ deg,
                              const int* __restrict__ batch, int N, int* __restrict__ gstart,
                              int DB) {
    int b = blockIdx.x;
    if (b < DB) {
        int i = b * 256 + threadIdx.x;
        if (i < E) atomicAdd(&deg[ei[E + i]], 1);
    } else {
        int g = (b - DB) * 256 + threadIdx.x;
        if (g > GRAPHS) return;
        int lo = 0, hi = N;
        while (lo < hi) {
            int mid = (lo + hi) >> 1;
            if (batch[mid] < g) lo = mid + 1; else hi = mid;
        }
        gstart[g] = lo;
    }
}

// ---------------- scan (degree = deg[i] + 1 for the self loop) ----------------
__global__ void scan_partial(const int* __restrict__ deg, int N, int* __restrict__ partial) {
    int t = blockIdx.x * blockDim.x + threadIdx.x;
    int chunk = (N + SCAN_T - 1) / SCAN_T;
    int b = t * chunk;
    int e = min(N, b + chunk);
    int s = 0;
    for (int i = b; i < e; ++i) s += deg[i] + 1;
    partial[t] = s;
}

__global__ void scan_block(int* __restrict__ partial) {   // 1 block, 1024 threads
    __shared__ int wsum[16];
    int t = threadIdx.x;
    int lane = t & 63, w = t >> 6;
    int orig = partial[t];
    int v = orig;
    #pragma unroll
    for (int o = 1; o < 64; o <<= 1) {
        int u = __shfl_up(v, o);
        if (lane >= o) v += u;
    }
    if (lane == 63) wsum[w] = v;
    __syncthreads();
    if (t == 0) {
        int run = 0;
        for (int i = 0; i < 16; ++i) { int x = wsum[i]; wsum[i] = run; run += x; }
    }
    __syncthreads();
    v += wsum[w];
    partial[t] = v - orig;   // exclusive prefix
}

// writes rowptr, fill (=segment start), and the self-loop entry at segment end
__global__ void scan_final(const int* __restrict__ deg, const int* __restrict__ partial,
                           int N, int* __restrict__ rowptr, int* __restrict__ fill,
                           int* __restrict__ csr_src) {
    int t = blockIdx.x * blockDim.x + threadIdx.x;
    int chunk = (N + SCAN_T - 1) / SCAN_T;
    int b = t * chunk;
    int e = min(N, b + chunk);
    int run = partial[t];
    for (int i = b; i < e; ++i) {
        rowptr[i] = run;
        fill[i] = run;
        int d = deg[i];
        csr_src[run + d] = i;   // self loop at end of segment
        run += d + 1;
    }
    if (t == SCAN_T - 1) rowptr[N] = run;
}

// ---------------- edge scatter: atomicExch so stores land (and stay) in L2 ----------------
// A plain 4B scattered store misses L2 and costs a full 64B HBM RMW (measured:
// WRITE_SIZE == 64B * E). atomicExch executes in the owning XCD's L2, allocating
// the line; the ~16 entries/line then coalesce and write back once.
__global__ void scatter_kernel(const int* __restrict__ ei, int E,
                               int* __restrict__ fill, int* __restrict__ csr_src) {
    int i = blockIdx.x * blockDim.x + threadIdx.x;
    if (i >= E) return;
    int s = ei[i], d = ei[E + i];
    int pos = atomicAdd(&fill[d], 1);
    atomicExch(&csr_src[pos], s);
}

// ---------------- GEMM + fused score epilogue; h stored as packed bf16 ----------------
// W staged transposed in LDS: coalesced stride-64 global loads, ds_write_b128
// stores (conflict-free), ds_read_b128 column reads (row stride K+4 floats).
template<int K>
__device__ __forceinline__ void gemm_body(float* smem,
                                          const float* __restrict__ x, const float* __restrict__ W,
                                          const float* __restrict__ asrc, const float* __restrict__ adst,
                                          unsigned* __restrict__ hb, float* __restrict__ es,
                                          float* __restrict__ ed, int N, int bid) {
    constexpr int ROWS = 16;
    constexpr int KP = K + 4;
    constexpr int K4 = K / 4;
    float* Ws = smem;              // [64][KP] transposed (col-major W)
    float* xs = smem + 64 * KP;    // [ROWS][K]
    int base = bid * ROWS;

    // stage W transposed: thread t owns col c=t&63, k-quad q = (t>>6) + 4*it
    {
        int c = threadIdx.x & 63;
        int q0 = threadIdx.x >> 6;
        #pragma unroll
        for (int it = 0; it < K4 / 4; ++it) {
            int q = q0 + 4 * it;
            float4 v;
            v.x = W[(4 * q + 0) * F + c];
            v.y = W[(4 * q + 1) * F + c];
            v.z = W[(4 * q + 2) * F + c];
            v.w = W[(4 * q + 3) * F + c];
            *(float4*)&Ws[c * KP + 4 * q] = v;
        }
    }
    int nrows = min(ROWS, N - base);
    float4* xs4 = (float4*)xs;
    const float4* x4 = (const float4*)x;
    for (int i = threadIdx.x; i < nrows * K4; i += 256) {
        int r = i / K4, k4 = i - r * K4;
        xs4[r * K4 + k4] = x4[(size_t)(base + r) * K4 + k4];
    }
    __syncthreads();

    int wave = threadIdx.x >> 6, lane = threadIdx.x & 63;
    float as_l = asrc[lane];
    float ad_l = adst[lane];
    const float4* wr = (const float4*)&Ws[lane * KP];
    for (int r = wave; r < nrows; r += 4) {
        const float4* xr = (const float4*)&xs[r * K];
        float a0 = 0.f, a1 = 0.f, a2 = 0.f, a3 = 0.f;
        #pragma unroll
        for (int k4 = 0; k4 < K4; ++k4) {
            float4 xv = xr[k4];
            float4 wv = wr[k4];
            a0 = fmaf(xv.x, wv.x, a0);
            a1 = fmaf(xv.y, wv.y, a1);
            a2 = fmaf(xv.z, wv.z, a2);
            a3 = fmaf(xv.w, wv.w, a3);
        }
        float acc = (a0 + a1) + (a2 + a3);
        // pack lane-pair accs to bf16x2, even lanes store 4B (coalesced 128B/row)
        unsigned ub = __float_as_uint(acc);
        unsigned rb = (ub + 0x7FFF + ((ub >> 16) & 1)) >> 16;   // RNE bf16 bits
        unsigned pb = (unsigned)__shfl_xor((int)rb, 1);
        if ((lane & 1) == 0)
            hb[(size_t)(base + r) * 32 + (lane >> 1)] = (pb << 16) | rb;
        float vs = acc * as_l;
        float vd = acc * ad_l;
        #pragma unroll
        for (int o = 32; o > 0; o >>= 1) {
            vs += __shfl_down(vs, o);
            vd += __shfl_down(vd, o);
        }
        if (lane == 0) { es[base + r] = vs; ed[base + r] = vd; }
    }
}

template<int K>
__global__ void gemm_kernel(const float* __restrict__ x, const float* __restrict__ W,
                            const float* __restrict__ asrc, const float* __restrict__ adst,
                            unsigned* __restrict__ hb, float* __restrict__ es,
                            float* __restrict__ ed, int N) {
    extern __shared__ float smem[];
    gemm_body<K>(smem, x, W, asrc, adst, hb, es, ed, N, blockIdx.x);
}

// ---------------- per-node segment softmax + aggregation (bf16 h gather) ----------------
__device__ __forceinline__ float unpack_h(unsigned pw, int lane) {
    return __uint_as_float((lane & 1) ? (pw & 0xFFFF0000u) : (pw << 16));
}

__global__ void gat_aggregate(const unsigned* __restrict__ hb, const float* __restrict__ es,
                              const float* __restrict__ ed, const int* __restrict__ rowptr,
                              const int* __restrict__ csr_src, const float* __restrict__ bias,
                              float* __restrict__ xout, int N) {
    __shared__ float2 sw[4][64];
    int wave = threadIdx.x >> 6, lane = threadIdx.x & 63;
    int node = blockIdx.x * 4 + wave;
    if (node >= N) return;
    int beg = rowptr[node], end = rowptr[node + 1];
    int cnt = end - beg;
    float edn = ed[node];
    int half = lane >> 1;
    float acc;

    if (cnt <= 64) {
        int s = 0;
        float e = -1e30f;
        if (lane < cnt) {
            s = csr_src[beg + lane];
            float t = es[s] + edn;
            e = t > 0.f ? t : 0.2f * t;
        }
        float m = e;
        #pragma unroll
        for (int o = 32; o > 0; o >>= 1) m = fmaxf(m, __shfl_xor(m, o));
        float w = (lane < cnt) ? __expf(e - m) : 0.f;
        float den = w;
        #pragma unroll
        for (int o = 32; o > 0; o >>= 1) den += __shfl_xor(den, o);
        sw[wave][lane] = make_float2(__int_as_float(s), w);
        float a0 = 0.f, a1 = 0.f, a2 = 0.f, a3 = 0.f;
        int i = 0;
        for (; i + 3 < cnt; i += 4) {
            float2 p0 = sw[wave][i];
            float2 p1 = sw[wave][i + 1];
            float2 p2 = sw[wave][i + 2];
            float2 p3 = sw[wave][i + 3];
            float h0 = unpack_h(hb[(size_t)__float_as_int(p0.x) * 32 + half], lane);
            float h1 = unpack_h(hb[(size_t)__float_as_int(p1.x) * 32 + half], lane);
            float h2 = unpack_h(hb[(size_t)__float_as_int(p2.x) * 32 + half], lane);
            float h3 = unpack_h(hb[(size_t)__float_as_int(p3.x) * 32 + half], lane);
            a0 = fmaf(p0.y, h0, a0);
            a1 = fmaf(p1.y, h1, a1);
            a2 = fmaf(p2.y, h2, a2);
            a3 = fmaf(p3.y, h3, a3);
        }
        for (; i < cnt; ++i) {
            float2 p = sw[wave][i];
            a0 = fmaf(p.y, unpack_h(hb[(size_t)__float_as_int(p.x) * 32 + half], lane), a0);
        }
        acc = ((a0 + a1) + (a2 + a3)) / (den + 1e-16f);
    } else {
        float m = -1e30f;
        for (int j = beg + lane; j < end; j += 64) {
            float e = es[csr_src[j]] + edn;
            e = e > 0.f ? e : 0.2f * e;
            m = fmaxf(m, e);
        }
        #pragma unroll
        for (int o = 32; o > 0; o >>= 1) m = fmaxf(m, __shfl_xor(m, o));
        float a = 0.f, den = 0.f;
        for (int j = beg; j < end; ++j) {
            int s = csr_src[j];
            float e = es[s] + edn;
            e = e > 0.f ? e : 0.2f * e;
            float w = __expf(e - m);
            den += w;
            a = fmaf(w, unpack_h(hb[(size_t)s * 32 + half], lane), a);
        }
        acc = a / (den + 1e-16f);
    }
    float v = acc + bias[lane];
    v = v > 0.f ? v : 0.f;   // relu
    xout[(size_t)node * F + lane] = v;
}

// ---------------- mean pooling: 4 blocks per graph, register accumulate ----------------
__global__ void pool_kernel(const float* __restrict__ x1, const float* __restrict__ x2,
                            const float* __restrict__ x3, const int* __restrict__ gstart,
                            float* __restrict__ pooled) {
    int g = blockIdx.x >> 2;
    int seg = blockIdx.x & 3;
    int f = threadIdx.x;               // 0..191
    int lane = f & 63;
    const float* src = (f < 64) ? x1 : (f < 128) ? x2 : x3;
    int lo = gstart[g], hi = gstart[g + 1];
    int len = hi - lo;
    int chunk = (len + 3) >> 2;
    int b = lo + seg * chunk;
    int e = min(hi, b + chunk);
    float s0 = 0.f, s1 = 0.f, s2 = 0.f, s3 = 0.f;
    int i = b;
    for (; i + 3 < e; i += 4) {
        s0 += src[(size_t)i * F + lane];
        s1 += src[(size_t)(i + 1) * F + lane];
        s2 += src[(size_t)(i + 2) * F + lane];
        s3 += src[(size_t)(i + 3) * F + lane];
    }
    for (; i < e; ++i) s0 += src[(size_t)i * F + lane];
    float s = (s0 + s1) + (s2 + s3);
    atomicAdd(&pooled[g * 192 + f], s);
}

// ---------------- final linear + softmax ----------------
__global__ void head_kernel(const float* __restrict__ pooled, const int* __restrict__ gstart,
                            const float* __restrict__ Wo, const float* __restrict__ bo,
                            float* __restrict__ out) {
    int g = blockIdx.x * blockDim.x + threadIdx.x;
    if (g >= GRAPHS) return;
    int cntg = gstart[g + 1] - gstart[g];
    float inv = 1.0f / fmaxf((float)cntg, 1.0f);
    float acc[CLASSES];
    #pragma unroll
    for (int c = 0; c < CLASSES; ++c) acc[c] = bo[c];
    for (int f = 0; f < 192; ++f) {
        float p = pooled[g * 192 + f] * inv;
        #pragma unroll
        for (int c = 0; c < CLASSES; ++c) acc[c] = fmaf(p, Wo[f * CLASSES + c], acc[c]);
    }
    float mx = acc[0];
    #pragma unroll
    for (int c = 1; c < CLASSES; ++c) mx = fmaxf(mx, acc[c]);
    float s = 0.f;
    #pragma unroll
    for (int c = 0; c < CLASSES; ++c) { acc[c] = __expf(acc[c] - mx); s += acc[c]; }
    float invs = 1.0f / s;
    #pragma unroll
    for (int c = 0; c < CLASSES; ++c) out[g * CLASSES + c] = acc[c] * invs;
}

extern "C" void kernel_launch(void* const* d_in, const int* in_sizes, int n_in,
                              void* d_out, int out_size, void* d_ws, size_t ws_size,
                              hipStream_t stream) {
    const float* x   = (const float*)d_in[0];
    const int* ei    = (const int*)d_in[1];
    const int* batch = (const int*)d_in[2];
    const float* W1  = (const float*)d_in[3];
    const float* a1s = (const float*)d_in[4];
    const float* a1d = (const float*)d_in[5];
    const float* b1  = (const float*)d_in[6];
    const float* W2  = (const float*)d_in[7];
    const float* a2s = (const float*)d_in[8];
    const float* a2d = (const float*)d_in[9];
    const float* b2  = (const float*)d_in[10];
    const float* W3  = (const float*)d_in[11];
    const float* a3s = (const float*)d_in[12];
    const float* a3d = (const float*)d_in[13];
    const float* b3  = (const float*)d_in[14];
    const float* Wo  = (const float*)d_in[15];
    const float* bo  = (const float*)d_in[16];
    float* out = (float*)d_out;

    const int N = in_sizes[2];          // #nodes
    const int E = in_sizes[1] / 2;      // real edges
    const int TOT = E + N;              // with self loops

    char* p = (char*)d_ws;
    auto alloc = [&](size_t bytes) { char* r = p; p += (bytes + 255) & ~(size_t)255; return r; };
    float* x1      = (float*)alloc((size_t)N * F * 4);
    float* x2      = (float*)alloc((size_t)N * F * 4);
    float* x3      = (float*)alloc((size_t)N * F * 4);
    unsigned* hb   = (unsigned*)alloc((size_t)N * 32 * 4);   // bf16x2 packed h
    float* es      = (float*)alloc((size_t)N * 4);
    float* ed      = (float*)alloc((size_t)N * 4);
    int* deg       = (int*)alloc((size_t)N * 4);
    int* rowptr    = (int*)alloc((size_t)(N + 1) * 4);
    int* fill      = (int*)alloc((size_t)N * 4);
    int* csr_src   = (int*)alloc((size_t)TOT * 4);
    int* partial   = (int*)alloc((size_t)SCAN_T * 4);
    float* pooled  = (float*)alloc((size_t)GRAPHS * 192 * 4);
    int* gstart    = (int*)alloc((size_t)(GRAPHS + 1) * 4);

    hipMemsetAsync(deg, 0, (size_t)N * 4, stream);
    hipMemsetAsync(pooled, 0, (size_t)GRAPHS * 192 * 4, stream);

    const int DB = (E + 255) / 256;
    const int GB = (N + 15) / 16;
    const size_t SM128 = (size_t)(64 * 132 + 16 * 128) * 4;   // 41984 B
    const size_t SM64  = (size_t)(64 * 68 + 16 * 64) * 4;     // 21504 B
    int node_blocks = (N + 3) / 4;

    // CSR build (deg over real edges; gbounds rides along; self-loops placed by scan)
    deg_gb_kernel<<<DB + 3, 256, 0, stream>>>(ei, E, deg, batch, N, gstart, DB);
    scan_partial<<<SCAN_T / 256, 256, 0, stream>>>(deg, N, partial);
    scan_block<<<1, SCAN_T, 0, stream>>>(partial);
    scan_final<<<SCAN_T / 256, 256, 0, stream>>>(deg, partial, N, rowptr, fill, csr_src);
    scatter_kernel<<<DB, 256, 0, stream>>>(ei, E, fill, csr_src);

    // layer 1
    gemm_kernel<128><<<GB, 256, SM128, stream>>>(x, W1, a1s, a1d, hb, es, ed, N);
    gat_aggregate<<<node_blocks, 256, 0, stream>>>(hb, es, ed, rowptr, csr_src, b1, x1, N);
    // layer 2
    gemm_kernel<64><<<GB, 256, SM64, stream>>>(x1, W2, a2s, a2d, hb, es, ed, N);
    gat_aggregate<<<node_blocks, 256, 0, stream>>>(hb, es, ed, rowptr, csr_src, b2, x2, N);
    // layer 3
    gemm_kernel<64><<<GB, 256, SM64, stream>>>(x2, W3, a3s, a3d, hb, es, ed, N);
    gat_aggregate<<<node_blocks, 256, 0, stream>>>(hb, es, ed, rowptr, csr_src, b3, x3, N);

    // readout
    pool_kernel<<<GRAPHS * 4, 192, 0, stream>>>(x1, x2, x3, gstart, pooled);
    head_kernel<<<(GRAPHS + 255) / 256, 256, 0, stream>>>(pooled, gstart, Wo, bo, out);
}

// Round 6
// 719.361 us; speedup vs baseline: 1.2438x; 1.1424x over previous
//
#include <hip/hip_runtime.h>
#include <hip/hip_bf16.h>

#define F 64
#define GRAPHS 512
#define CLASSES 10
#define SCAN_T 1024

// ---------------- deg (real edges only) + graph bounds fused ----------------
__global__ void deg_gb_kernel(const int* __restrict__ ei, int E, int* __restrict__ deg,
                              const int* __restrict__ batch, int N, int* __restrict__ gstart,
                              int DB) {
    int b = blockIdx.x;
    if (b < DB) {
        int i = b * 256 + threadIdx.x;
        if (i < E) atomicAdd(&deg[ei[E + i]], 1);
    } else {
        int g = (b - DB) * 256 + threadIdx.x;
        if (g > GRAPHS) return;
        int lo = 0, hi = N;
        while (lo < hi) {
            int mid = (lo + hi) >> 1;
            if (batch[mid] < g) lo = mid + 1; else hi = mid;
        }
        gstart[g] = lo;
    }
}

// ---------------- scan (degree = deg[i] + 1 for the self loop) ----------------
__global__ void scan_partial(const int* __restrict__ deg, int N, int* __restrict__ partial) {
    int t = blockIdx.x * blockDim.x + threadIdx.x;
    int chunk = (N + SCAN_T - 1) / SCAN_T;
    int b = t * chunk;
    int e = min(N, b + chunk);
    int s = 0;
    for (int i = b; i < e; ++i) s += deg[i] + 1;
    partial[t] = s;
}

__global__ void scan_block(int* __restrict__ partial) {   // 1 block, 1024 threads
    __shared__ int wsum[16];
    int t = threadIdx.x;
    int lane = t & 63, w = t >> 6;
    int orig = partial[t];
    int v = orig;
    #pragma unroll
    for (int o = 1; o < 64; o <<= 1) {
        int u = __shfl_up(v, o);
        if (lane >= o) v += u;
    }
    if (lane == 63) wsum[w] = v;
    __syncthreads();
    if (t == 0) {
        int run = 0;
        for (int i = 0; i < 16; ++i) { int x = wsum[i]; wsum[i] = run; run += x; }
    }
    __syncthreads();
    v += wsum[w];
    partial[t] = v - orig;   // exclusive prefix
}

// writes rowptr, fill (=segment start), and the self-loop entry at segment end
__global__ void scan_final(const int* __restrict__ deg, const int* __restrict__ partial,
                           int N, int* __restrict__ rowptr, int* __restrict__ fill,
                           int* __restrict__ csr_src) {
    int t = blockIdx.x * blockDim.x + threadIdx.x;
    int chunk = (N + SCAN_T - 1) / SCAN_T;
    int b = t * chunk;
    int e = min(N, b + chunk);
    int run = partial[t];
    for (int i = b; i < e; ++i) {
        rowptr[i] = run;
        fill[i] = run;
        int d = deg[i];
        csr_src[run + d] = i;   // self loop at end of segment
        run += d + 1;
    }
    if (t == SCAN_T - 1) rowptr[N] = run;
}

// ---------------- edge scatter (plain store; atomicExch measured slower, same WRITE) ----
__global__ void scatter_kernel(const int* __restrict__ ei, int E,
                               int* __restrict__ fill, int* __restrict__ csr_src) {
    int i = blockIdx.x * blockDim.x + threadIdx.x;
    if (i >= E) return;
    int s = ei[i], d = ei[E + i];
    int pos = atomicAdd(&fill[d], 1);
    csr_src[pos] = s;
}

// ---------------- GEMM + fused score epilogue; h packed bf16 via LDS flush ----------------
// W transposed in LDS (ds_read_b128 column reads). Inner loop swapped: one wv load
// feeds 4 independent row accumulators. h rows staged packed in LDS, then flushed
// block-cooperatively with full-wave contiguous dword stores (full 64B lines —
// avoids the partial-wave store write-around that cost 165MB WRITE_SIZE in R5).
template<int K>
__device__ __forceinline__ void gemm_body(float* smem,
                                          const float* __restrict__ x, const float* __restrict__ W,
                                          const float* __restrict__ asrc, const float* __restrict__ adst,
                                          unsigned* __restrict__ hb, float* __restrict__ es,
                                          float* __restrict__ ed, int N, int bid) {
    constexpr int ROWS = 16;
    constexpr int KP = K + 4;
    constexpr int K4 = K / 4;
    float* Ws = smem;                                  // [64][KP] transposed
    float* xs = smem + 64 * KP;                        // [ROWS][K]
    unsigned* hs = (unsigned*)(smem + 64 * KP + ROWS * K);  // [ROWS*32] packed bf16x2
    int base = bid * ROWS;

    // stage W transposed: coalesced row reads, per-lane column writes
    {
        int c = threadIdx.x & 63;
        int q0 = threadIdx.x >> 6;
        #pragma unroll
        for (int it = 0; it < K4 / 4; ++it) {
            int q = q0 + 4 * it;
            float4 v;
            v.x = W[(4 * q + 0) * F + c];
            v.y = W[(4 * q + 1) * F + c];
            v.z = W[(4 * q + 2) * F + c];
            v.w = W[(4 * q + 3) * F + c];
            *(float4*)&Ws[c * KP + 4 * q] = v;
        }
    }
    int nrows = min(ROWS, N - base);
    float4* xs4 = (float4*)xs;
    const float4* x4 = (const float4*)x;
    for (int i = threadIdx.x; i < nrows * K4; i += 256) {
        int r = i / K4, k4 = i - r * K4;
        xs4[r * K4 + k4] = x4[(size_t)(base + r) * K4 + k4];
    }
    __syncthreads();

    int wave = threadIdx.x >> 6, lane = threadIdx.x & 63;
    float as_l = asrc[lane];
    float ad_l = adst[lane];
    const float4* wr = (const float4*)&Ws[lane * KP];
    const float4* xr0 = (const float4*)&xs[(wave + 0) * K];
    const float4* xr1 = (const float4*)&xs[(wave + 4) * K];
    const float4* xr2 = (const float4*)&xs[(wave + 8) * K];
    const float4* xr3 = (const float4*)&xs[(wave + 12) * K];
    float a0 = 0.f, a1 = 0.f, a2 = 0.f, a3 = 0.f;
    #pragma unroll 8
    for (int k4 = 0; k4 < K4; ++k4) {
        float4 wv = wr[k4];
        float4 v0 = xr0[k4], v1 = xr1[k4], v2 = xr2[k4], v3 = xr3[k4];
        a0 = fmaf(v0.x, wv.x, fmaf(v0.y, wv.y, fmaf(v0.z, wv.z, fmaf(v0.w, wv.w, a0))));
        a1 = fmaf(v1.x, wv.x, fmaf(v1.y, wv.y, fmaf(v1.z, wv.z, fmaf(v1.w, wv.w, a1))));
        a2 = fmaf(v2.x, wv.x, fmaf(v2.y, wv.y, fmaf(v2.z, wv.z, fmaf(v2.w, wv.w, a2))));
        a3 = fmaf(v3.x, wv.x, fmaf(v3.y, wv.y, fmaf(v3.z, wv.z, fmaf(v3.w, wv.w, a3))));
    }
    float accs[4] = {a0, a1, a2, a3};
    #pragma unroll
    for (int rr = 0; rr < 4; ++rr) {
        int r = wave + 4 * rr;
        float acc = accs[rr];
        unsigned ub = __float_as_uint(acc);
        unsigned rb = (ub + 0x7FFF + ((ub >> 16) & 1)) >> 16;   // RNE bf16 bits
        unsigned pb = (unsigned)__shfl_xor((int)rb, 1);
        if ((lane & 1) == 0) hs[r * 32 + (lane >> 1)] = (pb << 16) | rb;
        float vs = acc * as_l;
        float vd = acc * ad_l;
        #pragma unroll
        for (int o = 32; o > 0; o >>= 1) {
            vs += __shfl_down(vs, o);
            vd += __shfl_down(vd, o);
        }
        if (lane == 0 && r < nrows) { es[base + r] = vs; ed[base + r] = vd; }
    }
    __syncthreads();
    // coalesced full-wave flush: nrows*32 contiguous dwords
    unsigned* hbase = hb + (size_t)base * 32;
    for (int i = threadIdx.x; i < nrows * 32; i += 256) hbase[i] = hs[i];
}

template<int K>
__global__ void gemm_kernel(const float* __restrict__ x, const float* __restrict__ W,
                            const float* __restrict__ asrc, const float* __restrict__ adst,
                            unsigned* __restrict__ hb, float* __restrict__ es,
                            float* __restrict__ ed, int N) {
    extern __shared__ float smem[];
    gemm_body<K>(smem, x, W, asrc, adst, hb, es, ed, N, blockIdx.x);
}

// ---------------- per-node segment softmax + aggregation (bf16 h gather) ----------------
__device__ __forceinline__ float unpack_h(unsigned pw, int lane) {
    return __uint_as_float((lane & 1) ? (pw & 0xFFFF0000u) : (pw << 16));
}

__global__ void gat_aggregate(const unsigned* __restrict__ hb, const float* __restrict__ es,
                              const float* __restrict__ ed, const int* __restrict__ rowptr,
                              const int* __restrict__ csr_src, const float* __restrict__ bias,
                              float* __restrict__ xout, int N) {
    __shared__ float2 sw[4][64];
    int wave = threadIdx.x >> 6, lane = threadIdx.x & 63;
    int node = blockIdx.x * 4 + wave;
    if (node >= N) return;
    int beg = rowptr[node], end = rowptr[node + 1];
    int cnt = end - beg;
    float edn = ed[node];
    int half = lane >> 1;
    float acc;

    if (cnt <= 64) {
        int s = 0;
        float e = -1e30f;
        if (lane < cnt) {
            s = csr_src[beg + lane];
            float t = es[s] + edn;
            e = t > 0.f ? t : 0.2f * t;
        }
        float m = e;
        #pragma unroll
        for (int o = 32; o > 0; o >>= 1) m = fmaxf(m, __shfl_xor(m, o));
        float w = (lane < cnt) ? __expf(e - m) : 0.f;
        float den = w;
        #pragma unroll
        for (int o = 32; o > 0; o >>= 1) den += __shfl_xor(den, o);
        sw[wave][lane] = make_float2(__int_as_float(s), w);
        float a0 = 0.f, a1 = 0.f, a2 = 0.f, a3 = 0.f;
        int i = 0;
        for (; i + 3 < cnt; i += 4) {
            float2 p0 = sw[wave][i];
            float2 p1 = sw[wave][i + 1];
            float2 p2 = sw[wave][i + 2];
            float2 p3 = sw[wave][i + 3];
            float h0 = unpack_h(hb[(size_t)__float_as_int(p0.x) * 32 + half], lane);
            float h1 = unpack_h(hb[(size_t)__float_as_int(p1.x) * 32 + half], lane);
            float h2 = unpack_h(hb[(size_t)__float_as_int(p2.x) * 32 + half], lane);
            float h3 = unpack_h(hb[(size_t)__float_as_int(p3.x) * 32 + half], lane);
            a0 = fmaf(p0.y, h0, a0);
            a1 = fmaf(p1.y, h1, a1);
            a2 = fmaf(p2.y, h2, a2);
            a3 = fmaf(p3.y, h3, a3);
        }
        for (; i < cnt; ++i) {
            float2 p = sw[wave][i];
            a0 = fmaf(p.y, unpack_h(hb[(size_t)__float_as_int(p.x) * 32 + half], lane), a0);
        }
        acc = ((a0 + a1) + (a2 + a3)) / (den + 1e-16f);
    } else {
        float m = -1e30f;
        for (int j = beg + lane; j < end; j += 64) {
            float e = es[csr_src[j]] + edn;
            e = e > 0.f ? e : 0.2f * e;
            m = fmaxf(m, e);
        }
        #pragma unroll
        for (int o = 32; o > 0; o >>= 1) m = fmaxf(m, __shfl_xor(m, o));
        float a = 0.f, den = 0.f;
        for (int j = beg; j < end; ++j) {
            int s = csr_src[j];
            float e = es[s] + edn;
            e = e > 0.f ? e : 0.2f * e;
            float w = __expf(e - m);
            den += w;
            a = fmaf(w, unpack_h(hb[(size_t)s * 32 + half], lane), a);
        }
        acc = a / (den + 1e-16f);
    }
    float v = acc + bias[lane];
    v = v > 0.f ? v : 0.f;   // relu
    xout[(size_t)node * F + lane] = v;
}

// ---------------- mean pooling: 4 blocks per graph, register accumulate ----------------
__global__ void pool_kernel(const float* __restrict__ x1, const float* __restrict__ x2,
                            const float* __restrict__ x3, const int* __restrict__ gstart,
                            float* __restrict__ pooled) {
    int g = blockIdx.x >> 2;
    int seg = blockIdx.x & 3;
    int f = threadIdx.x;               // 0..191
    int lane = f & 63;
    const float* src = (f < 64) ? x1 : (f < 128) ? x2 : x3;
    int lo = gstart[g], hi = gstart[g + 1];
    int len = hi - lo;
    int chunk = (len + 3) >> 2;
    int b = lo + seg * chunk;
    int e = min(hi, b + chunk);
    float s0 = 0.f, s1 = 0.f, s2 = 0.f, s3 = 0.f;
    int i = b;
    for (; i + 3 < e; i += 4) {
        s0 += src[(size_t)i * F + lane];
        s1 += src[(size_t)(i + 1) * F + lane];
        s2 += src[(size_t)(i + 2) * F + lane];
        s3 += src[(size_t)(i + 3) * F + lane];
    }
    for (; i < e; ++i) s0 += src[(size_t)i * F + lane];
    float s = (s0 + s1) + (s2 + s3);
    atomicAdd(&pooled[g * 192 + f], s);
}

// ---------------- final linear + softmax ----------------
__global__ void head_kernel(const float* __restrict__ pooled, const int* __restrict__ gstart,
                            const float* __restrict__ Wo, const float* __restrict__ bo,
                            float* __restrict__ out) {
    int g = blockIdx.x * blockDim.x + threadIdx.x;
    if (g >= GRAPHS) return;
    int cntg = gstart[g + 1] - gstart[g];
    float inv = 1.0f / fmaxf((float)cntg, 1.0f);
    float acc[CLASSES];
    #pragma unroll
    for (int c = 0; c < CLASSES; ++c) acc[c] = bo[c];
    for (int f = 0; f < 192; ++f) {
        float p = pooled[g * 192 + f] * inv;
        #pragma unroll
        for (int c = 0; c < CLASSES; ++c) acc[c] = fmaf(p, Wo[f * CLASSES + c], acc[c]);
    }
    float mx = acc[0];
    #pragma unroll
    for (int c = 1; c < CLASSES; ++c) mx = fmaxf(mx, acc[c]);
    float s = 0.f;
    #pragma unroll
    for (int c = 0; c < CLASSES; ++c) { acc[c] = __expf(acc[c] - mx); s += acc[c]; }
    float invs = 1.0f / s;
    #pragma unroll
    for (int c = 0; c < CLASSES; ++c) out[g * CLASSES + c] = acc[c] * invs;
}

extern "C" void kernel_launch(void* const* d_in, const int* in_sizes, int n_in,
                              void* d_out, int out_size, void* d_ws, size_t ws_size,
                              hipStream_t stream) {
    const float* x   = (const float*)d_in[0];
    const int* ei    = (const int*)d_in[1];
    const int* batch = (const int*)d_in[2];
    const float* W1  = (const float*)d_in[3];
    const float* a1s = (const float*)d_in[4];
    const float* a1d = (const float*)d_in[5];
    const float* b1  = (const float*)d_in[6];
    const float* W2  = (const float*)d_in[7];
    const float* a2s = (const float*)d_in[8];
    const float* a2d = (const float*)d_in[9];
    const float* b2  = (const float*)d_in[10];
    const float* W3  = (const float*)d_in[11];
    const float* a3s = (const float*)d_in[12];
    const float* a3d = (const float*)d_in[13];
    const float* b3  = (const float*)d_in[14];
    const float* Wo  = (const float*)d_in[15];
    const float* bo  = (const float*)d_in[16];
    float* out = (float*)d_out;

    const int N = in_sizes[2];          // #nodes
    const int E = in_sizes[1] / 2;      // real edges
    const int TOT = E + N;              // with self loops

    char* p = (char*)d_ws;
    auto alloc = [&](size_t bytes) { char* r = p; p += (bytes + 255) & ~(size_t)255; return r; };
    float* x1      = (float*)alloc((size_t)N * F * 4);
    float* x2      = (float*)alloc((size_t)N * F * 4);
    float* x3      = (float*)alloc((size_t)N * F * 4);
    unsigned* hb   = (unsigned*)alloc((size_t)N * 32 * 4);   // bf16x2 packed h
    float* es      = (float*)alloc((size_t)N * 4);
    float* ed      = (float*)alloc((size_t)N * 4);
    int* deg       = (int*)alloc((size_t)N * 4);
    int* rowptr    = (int*)alloc((size_t)(N + 1) * 4);
    int* fill      = (int*)alloc((size_t)N * 4);
    int* csr_src   = (int*)alloc((size_t)TOT * 4);
    int* partial   = (int*)alloc((size_t)SCAN_T * 4);
    float* pooled  = (float*)alloc((size_t)GRAPHS * 192 * 4);
    int* gstart    = (int*)alloc((size_t)(GRAPHS + 1) * 4);

    hipMemsetAsync(deg, 0, (size_t)N * 4, stream);
    hipMemsetAsync(pooled, 0, (size_t)GRAPHS * 192 * 4, stream);

    const int DB = (E + 255) / 256;
    const int GB = (N + 15) / 16;
    const size_t SM128 = (size_t)(64 * 132 + 16 * 128) * 4 + 2048;   // W + x + h-stage
    const size_t SM64  = (size_t)(64 * 68 + 16 * 64) * 4 + 2048;
    int node_blocks = (N + 3) / 4;

    // CSR build (deg over real edges; gbounds rides along; self-loops placed by scan)
    deg_gb_kernel<<<DB + 3, 256, 0, stream>>>(ei, E, deg, batch, N, gstart, DB);
    scan_partial<<<SCAN_T / 256, 256, 0, stream>>>(deg, N, partial);
    scan_block<<<1, SCAN_T, 0, stream>>>(partial);
    scan_final<<<SCAN_T / 256, 256, 0, stream>>>(deg, partial, N, rowptr, fill, csr_src);
    scatter_kernel<<<DB, 256, 0, stream>>>(ei, E, fill, csr_src);

    // layer 1
    gemm_kernel<128><<<GB, 256, SM128, stream>>>(x, W1, a1s, a1d, hb, es, ed, N);
    gat_aggregate<<<node_blocks, 256, 0, stream>>>(hb, es, ed, rowptr, csr_src, b1, x1, N);
    // layer 2
    gemm_kernel<64><<<GB, 256, SM64, stream>>>(x1, W2, a2s, a2d, hb, es, ed, N);
    gat_aggregate<<<node_blocks, 256, 0, stream>>>(hb, es, ed, rowptr, csr_src, b2, x2, N);
    // layer 3
    gemm_kernel<64><<<GB, 256, SM64, stream>>>(x2, W3, a3s, a3d, hb, es, ed, N);
    gat_aggregate<<<node_blocks, 256, 0, stream>>>(hb, es, ed, rowptr, csr_src, b3, x3, N);

    // readout
    pool_kernel<<<GRAPHS * 4, 192, 0, stream>>>(x1, x2, x3, gstart, pooled);
    head_kernel<<<(GRAPHS + 255) / 256, 256, 0, stream>>>(pooled, gstart, Wo, bo, out);
}